// Round 2
// baseline (336.315 us; speedup 1.0000x reference)
//
#include <hip/hip_runtime.h>

typedef _Float16 half8 __attribute__((ext_vector_type(8)));
typedef _Float16 half4_t __attribute__((ext_vector_type(4)));
typedef float floatx4 __attribute__((ext_vector_type(4)));

// LDS tile: 128 rows x 128 halves (256 B rows, no pad). Bank-conflict-free via
// XOR swizzle: 16B-slot index ^= (row & 7)  <=>  half-col ^= (row&7)<<3.
__device__ __forceinline__ int swz(int row, int col) {
    return row * 128 + (col ^ ((row & 7) << 3));
}

// One prep kernel: blocks [0,96) repack W1/W2 to MFMA A-frag order (fp16),
// blocks [96,..) convert x to fp16 (xh = L2-resident 6.4 MB copy).
__global__ __launch_bounds__(256) void prep_kernel(
    const float* __restrict__ x,
    const float* __restrict__ W1, const float* __restrict__ W2,
    _Float16* __restrict__ wsh, _Float16* __restrict__ xh, int n_x8)
{
    int b = blockIdx.x;
    if (b < 96) {
        int tid = b * 256 + threadIdx.x;
        if (tid < 16384) {                    // W1 cols 1..128: 8 mtiles x 4 kb x 512
            int c = tid >> 9, r = tid & 511;
            int L = r >> 3, jj = r & 7;
            int mt = c >> 2, kb = c & 3;
            int n = mt * 16 + (L & 15);
            int k = kb * 32 + (L >> 4) * 8 + jj;
            wsh[tid] = (_Float16)W1[n * 129 + 1 + k];
        } else {                              // W2: 4 mtiles x 4 kb x 512
            int t = tid - 16384;
            int c = t >> 9, r = t & 511;
            int L = r >> 3, jj = r & 7;
            int mt = c >> 2, kb = c & 3;
            int i = mt * 16 + (L & 15);
            int j = kb * 32 + (L >> 4) * 8 + jj;
            wsh[tid] = (_Float16)W2[i * 128 + j];
        }
    } else {
        int t2 = (b - 96) * 256 + threadIdx.x;
        if (t2 < n_x8) {
            const float4* p = (const float4*)(x + (size_t)t2 * 8);
            float4 v0 = p[0], v1 = p[1];
            half8 h = {(_Float16)v0.x, (_Float16)v0.y, (_Float16)v0.z, (_Float16)v0.w,
                       (_Float16)v1.x, (_Float16)v1.y, (_Float16)v1.z, (_Float16)v1.w};
            *(half8*)(xh + (size_t)t2 * 8) = h;
        }
    }
}

// Persistent-block pipelined version: grid = 1024 blocks, each grid-strides
// over 128-edge tiles. Next tile's random gather (ei -> node rows) is issued
// DURING the current tile's MFMA phases, so the ~200-900 cyc gather latency
// is barrier-exposed only once per block (prologue) instead of once per tile.
__global__ __launch_bounds__(256, 4) void edge_mlp_kernel(
    const _Float16* __restrict__ xh,
    const int* __restrict__ ei,
    const float* __restrict__ ew,
    const float* __restrict__ W1, const float* __restrict__ b1,
    const float* __restrict__ b2,
    const float* __restrict__ W3, const float* __restrict__ b3,
    const _Float16* __restrict__ wf,
    float* __restrict__ out, int E)
{
    // hA holds [edge][k] fp16 features for layer 1; after a full barrier it is
    // REUSED as [edge][n] hidden-1 storage (all reads complete before writes).
    __shared__ __align__(16) _Float16 hA[128 * 128];
    __shared__ float s_ew[128];
    __shared__ float s_b1[128];
    __shared__ float s_c0[128];   // W1[:,0] (edge-weight column, rank-1 epilogue)
    __shared__ float s_b2[64];
    __shared__ float s_w3[64];
    __shared__ float s_out[4][128];

    const int tid = threadIdx.x;

    if (tid < 128) {
        s_b1[tid] = b1[tid];
        s_c0[tid] = W1[tid * 129];
    } else if (tid < 192) {
        int i = tid - 128;
        s_b2[i] = b2[i];
        s_w3[i] = W3[i];
    }
    const float b3v = b3[0];

    const int lane = tid & 63;
    const int wave = tid >> 6;
    const int lrow = lane & 15;
    const int quad = lane >> 4;

    // W1 A-frags: persistent across all tiles of this block (32 VGPR).
    half8 afr[2][4];
#pragma unroll
    for (int mi = 0; mi < 2; ++mi)
#pragma unroll
        for (int kb = 0; kb < 4; ++kb)
            afr[mi][kb] = *(const half8*)(wf + ((2 * wave + mi) * 4 + kb) * 512 + lane * 8);

    const int T = (E + 127) >> 7;
    const int stride = gridDim.x;
    int t = blockIdx.x;

    // Gather-thread mapping: edge row = tid&127, part = tid>>7 (waves 0/1 src,
    // 2/3 tgt) -> 8 consecutive rows per 8-lane phase hit 8 distinct swizzled
    // 16B slots: conflict-free ds_write_b128.
    const int part = tid >> 7;
    const int e_loc = tid & 127;
    const int r7 = (e_loc & 7) << 3;

    half8 R[8];          // prefetched node row for the upcoming tile
    float ewr = 0.f;

    // ---- prologue: gather tile t into registers ----
    {
        int e = t * 128 + e_loc; if (e >= E) e = E - 1;
        int node = ei[(size_t)part * E + e];
        const _Float16* rp = xh + (size_t)node * 64;
#pragma unroll
        for (int q = 0; q < 8; ++q)
            R[q] = *(const half8*)(rp + q * 8);
        if (tid < 128) ewr = ew[e];
    }

    for (; t < T; t += stride) {
        // ---- stage prefetched tile into LDS (swizzled) ----
        {
            _Float16* dst = &hA[e_loc * 128];
            const int base = part * 64;
#pragma unroll
            for (int q = 0; q < 8; ++q)
                *(half8*)(dst + ((base + q * 8) ^ r7)) = R[q];
            if (tid < 128) s_ew[tid] = ewr;
        }
        __syncthreads();

        // ---- issue next tile's edge-index load (latency hides under L1) ----
        int tn = t + stride;
        int pe;
        {
            int e2 = ((tn < T) ? tn : t) * 128 + e_loc;
            if (e2 >= E) e2 = E - 1;
            pe = e2;
        }
        int nnode = ei[(size_t)part * E + pe];

        // ---- layer 1: D1T[n][e] = W1h(128n x 128k) x hA^T(128k x 128e) ----
        half4_t h1v[2][8];
#pragma unroll
        for (int nt = 0; nt < 8; ++nt) {
            int row = nt * 16 + lrow;
            half8 bfr[4];
#pragma unroll
            for (int kb = 0; kb < 4; ++kb)
                bfr[kb] = *(const half8*)(&hA[swz(row, kb * 32 + quad * 8)]);
            float ewv = s_ew[row];
#pragma unroll
            for (int mi = 0; mi < 2; ++mi) {
                floatx4 a = {0.f, 0.f, 0.f, 0.f};
#pragma unroll
                for (int kb = 0; kb < 4; ++kb)
                    a = __builtin_amdgcn_mfma_f32_16x16x32_f16(afr[mi][kb], bfr[kb], a, 0, 0, 0);
                int nb = (2 * wave + mi) * 16 + quad * 4;
                half4_t hv;
#pragma unroll
                for (int r = 0; r < 4; ++r) {
                    float v = a[r] + s_b1[nb + r] + ewv * s_c0[nb + r];
                    hv[r] = (_Float16)fmaxf(v, 0.f);
                }
                h1v[mi][nt] = hv;
            }
        }

        // ---- issue next tile's node-row loads (hide under h1-write + L2) ----
        {
            const _Float16* rp = xh + (size_t)nnode * 64;
#pragma unroll
            for (int q = 0; q < 8; ++q)
                R[q] = *(const half8*)(rp + q * 8);
            if (tid < 128) ewr = ew[pe];
        }
        __syncthreads();   // all hA feature reads complete — safe to alias

        // ---- write hidden1 (fp16) into hA space as [e][n], swizzled ----
#pragma unroll
        for (int mi = 0; mi < 2; ++mi) {
            int nb = (2 * wave + mi) * 16 + quad * 4;
#pragma unroll
            for (int nt = 0; nt < 8; ++nt) {
                int row = nt * 16 + lrow;
                *(half4_t*)(&hA[swz(row, nb)]) = h1v[mi][nt];
            }
        }
        __syncthreads();

        // ---- layer 2 (+fused layer 3): wave handles i-tile = wave ----
        half8 a2fr[4];
#pragma unroll
        for (int kb = 0; kb < 4; ++kb)
            a2fr[kb] = *(const half8*)(wf + 16384 + (wave * 4 + kb) * 512 + lane * 8);

#pragma unroll
        for (int nt = 0; nt < 8; ++nt) {
            int row = nt * 16 + lrow;
            half8 bfr[4];
#pragma unroll
            for (int kb = 0; kb < 4; ++kb)
                bfr[kb] = *(const half8*)(&hA[swz(row, kb * 32 + quad * 8)]);
            floatx4 a = {0.f, 0.f, 0.f, 0.f};
#pragma unroll
            for (int kb = 0; kb < 4; ++kb)
                a = __builtin_amdgcn_mfma_f32_16x16x32_f16(a2fr[kb], bfr[kb], a, 0, 0, 0);
            int ib = wave * 16 + quad * 4;
            float p = 0.f;
#pragma unroll
            for (int r = 0; r < 4; ++r)
                p += fmaxf(a[r] + s_b2[ib + r], 0.f) * s_w3[ib + r];
            p += __shfl_xor(p, 16, 64);
            p += __shfl_xor(p, 32, 64);
            if (quad == 0) s_out[wave][nt * 16 + lrow] = p;
        }
        __syncthreads();

        if (tid < 128) {
            int oe = t * 128 + tid;
            if (oe < E)
                out[oe] = b3v + s_out[0][tid] + s_out[1][tid]
                              + s_out[2][tid] + s_out[3][tid];
        }
        __syncthreads();   // protect hA/s_out before next tile's staging
    }
}

extern "C" void kernel_launch(void* const* d_in, const int* in_sizes, int n_in,
                              void* d_out, int out_size, void* d_ws, size_t ws_size,
                              hipStream_t stream) {
    const float* x  = (const float*)d_in[0];
    const int*   ei = (const int*)d_in[1];   // int32 (verified round 1)
    const float* ew = (const float*)d_in[2];
    const float* W1 = (const float*)d_in[3];
    const float* b1 = (const float*)d_in[4];
    const float* W2 = (const float*)d_in[5];
    const float* b2 = (const float*)d_in[6];
    const float* W3 = (const float*)d_in[7];
    const float* b3 = (const float*)d_in[8];
    float* out = (float*)d_out;
    const int E = in_sizes[2];               // n_edges
    const int n_x = in_sizes[0];             // 3.2M floats
    const int n_x8 = n_x / 8;

    _Float16* wsh = (_Float16*)d_ws;                 // 24576 halves = 48 KiB
    _Float16* xh  = (_Float16*)((char*)d_ws + 49152); // fp16 x copy, 6.4 MB

    int xblk = (n_x8 + 255) / 256;
    prep_kernel<<<96 + xblk, 256, 0, stream>>>(x, W1, W2, wsh, xh, n_x8);

    int T = (E + 127) / 128;
    int nblk = T < 1024 ? T : 1024;
    edge_mlp_kernel<<<nblk, 256, 0, stream>>>(xh, ei, ew, W1, b1, b2, W3, b3,
                                              wsh, out, E);
}

// Round 3
// 236.922 us; speedup vs baseline: 1.4195x; 1.4195x over previous
//
#include <hip/hip_runtime.h>

typedef _Float16 half8 __attribute__((ext_vector_type(8)));
typedef _Float16 half4_t __attribute__((ext_vector_type(4)));
typedef float floatx4 __attribute__((ext_vector_type(4)));

// LDS tile: 64 rows x 128 halves (256 B rows, no pad). XOR swizzle:
// 16B-slot index ^= (row & 7)  <=>  half-col ^= (row&7)<<3.
// Removes the genuine 4-way conflict spots; residual counter value is the
// benign 2-lane/bank wave64 floor (counted but timing-free, m136).
__device__ __forceinline__ int swz(int row, int col) {
    return row * 128 + (col ^ ((row & 7) << 3));
}

// One prep kernel: blocks [0,96) repack W1/W2 to MFMA A-frag order (fp16),
// blocks [96,..) convert x to fp16 (xh = L2/L3-resident 6.4 MB copy).
__global__ __launch_bounds__(256) void prep_kernel(
    const float* __restrict__ x,
    const float* __restrict__ W1, const float* __restrict__ W2,
    _Float16* __restrict__ wsh, _Float16* __restrict__ xh, int n_x8)
{
    int b = blockIdx.x;
    if (b < 96) {
        int tid = b * 256 + threadIdx.x;
        if (tid < 16384) {                    // W1 cols 1..128: 8 mtiles x 4 kb x 512
            int c = tid >> 9, r = tid & 511;
            int L = r >> 3, jj = r & 7;
            int mt = c >> 2, kb = c & 3;
            int n = mt * 16 + (L & 15);
            int k = kb * 32 + (L >> 4) * 8 + jj;
            wsh[tid] = (_Float16)W1[n * 129 + 1 + k];
        } else {                              // W2: 4 mtiles x 4 kb x 512
            int t = tid - 16384;
            int c = t >> 9, r = t & 511;
            int L = r >> 3, jj = r & 7;
            int mt = c >> 2, kb = c & 3;
            int i = mt * 16 + (L & 15);
            int j = kb * 32 + (L >> 4) * 8 + jj;
            wsh[tid] = (_Float16)W2[i * 128 + j];
        }
    } else {
        int t2 = (b - 96) * 256 + threadIdx.x;
        if (t2 < n_x8) {
            const float4* p = (const float4*)(x + (size_t)t2 * 8);
            float4 v0 = p[0], v1 = p[1];
            half8 h = {(_Float16)v0.x, (_Float16)v0.y, (_Float16)v0.z, (_Float16)v0.w,
                       (_Float16)v1.x, (_Float16)v1.y, (_Float16)v1.z, (_Float16)v1.w};
            *(half8*)(xh + (size_t)t2 * 8) = h;
        }
    }
}

// 64-edge tiles, ~19 KB LDS -> 8 blocks/CU (32 waves = full occupancy).
// Latency hiding comes from inter-block overlap, not intra-block prefetch
// (register prefetch across barriers spilled catastrophically in round 2).
__global__ __launch_bounds__(256, 8) void edge_mlp_kernel(
    const _Float16* __restrict__ xh,
    const int* __restrict__ ei,
    const float* __restrict__ ew,
    const float* __restrict__ W1, const float* __restrict__ b1,
    const float* __restrict__ b2,
    const float* __restrict__ W3, const float* __restrict__ b3,
    const _Float16* __restrict__ wf,
    float* __restrict__ out, int E)
{
    // hA holds [edge][k] fp16 features for layer 1; after a full barrier it is
    // REUSED as [edge][n] hidden-1 storage (all reads complete before writes).
    __shared__ __align__(16) _Float16 hA[64 * 128];
    __shared__ float s_ew[64];
    __shared__ float s_b1[128];
    __shared__ float s_c0[128];   // W1[:,0] (edge-weight column, rank-1 epilogue)
    __shared__ float s_b2[64];
    __shared__ float s_w3[64];
    __shared__ float s_out[4][64];

    const int tid = threadIdx.x;
    const int e_blk = blockIdx.x * 64;

    if (tid < 128) {
        s_b1[tid] = b1[tid];
        s_c0[tid] = W1[tid * 129];
    } else if (tid < 192) {
        int i = tid - 128;
        s_b2[i] = b2[i];
        s_w3[i] = W3[i];
    }

    // ---- gather fp16 node rows -> hA: k 0..63 = src, 64..127 = tgt ----
    // thread t: edge row = t&63, part = (t>>6)&1, half-row = t>>7.
    // Each thread stages 64 B (4 x half8). Within each 8-lane phase, 8
    // consecutive rows hit 8 distinct swizzled 16B slots: conflict-free.
    {
        int e_loc = tid & 63;
        int part = (tid >> 6) & 1;
        int half = tid >> 7;
        int e = e_blk + e_loc; if (e >= E) e = E - 1;
        int node = ei[(size_t)part * E + e];
        const _Float16* rp = xh + (size_t)node * 64 + half * 32;
        int r7 = (e_loc & 7) << 3;
        _Float16* dst = &hA[e_loc * 128];
        int base = part * 64 + half * 32;
#pragma unroll
        for (int q = 0; q < 4; ++q)
            *(half8*)(dst + ((base + q * 8) ^ r7)) = *(const half8*)(rp + q * 8);
        if (tid < 64) s_ew[tid] = ew[e];
    }
    __syncthreads();

    const int lane = tid & 63;
    const int wave = tid >> 6;
    const int lrow = lane & 15;
    const int quad = lane >> 4;

    // ---- layer 1: D1T[n][e] = W1h(128n x 128k) x hA^T(128k x 64e) ----
    half8 afr[2][4];
#pragma unroll
    for (int mi = 0; mi < 2; ++mi)
#pragma unroll
        for (int kb = 0; kb < 4; ++kb)
            afr[mi][kb] = *(const half8*)(wf + ((2 * wave + mi) * 4 + kb) * 512 + lane * 8);

    half4_t h1v[2][4];
#pragma unroll
    for (int nt = 0; nt < 4; ++nt) {
        int row = nt * 16 + lrow;
        half8 bfr[4];
#pragma unroll
        for (int kb = 0; kb < 4; ++kb)
            bfr[kb] = *(const half8*)(&hA[swz(row, kb * 32 + quad * 8)]);
        float ewv = s_ew[row];
#pragma unroll
        for (int mi = 0; mi < 2; ++mi) {
            floatx4 a = {0.f, 0.f, 0.f, 0.f};
#pragma unroll
            for (int kb = 0; kb < 4; ++kb)
                a = __builtin_amdgcn_mfma_f32_16x16x32_f16(afr[mi][kb], bfr[kb], a, 0, 0, 0);
            int nb = (2 * wave + mi) * 16 + quad * 4;
            half4_t hv;
#pragma unroll
            for (int r = 0; r < 4; ++r) {
                float v = a[r] + s_b1[nb + r] + ewv * s_c0[nb + r];
                hv[r] = (_Float16)fmaxf(v, 0.f);
            }
            h1v[mi][nt] = hv;
        }
    }
    __syncthreads();   // all hA feature reads complete — safe to alias

    // ---- write hidden1 (fp16) into hA space as [e][n], swizzled ----
#pragma unroll
    for (int mi = 0; mi < 2; ++mi) {
        int nb = (2 * wave + mi) * 16 + quad * 4;
#pragma unroll
        for (int nt = 0; nt < 4; ++nt) {
            int row = nt * 16 + lrow;
            *(half4_t*)(&hA[swz(row, nb)]) = h1v[mi][nt];
        }
    }
    __syncthreads();

    // ---- layer 2 (+fused layer 3): wave handles i-tile = wave ----
    half8 a2fr[4];
#pragma unroll
    for (int kb = 0; kb < 4; ++kb)
        a2fr[kb] = *(const half8*)(wf + 16384 + (wave * 4 + kb) * 512 + lane * 8);

#pragma unroll
    for (int nt = 0; nt < 4; ++nt) {
        int row = nt * 16 + lrow;
        half8 bfr[4];
#pragma unroll
        for (int kb = 0; kb < 4; ++kb)
            bfr[kb] = *(const half8*)(&hA[swz(row, kb * 32 + quad * 8)]);
        floatx4 a = {0.f, 0.f, 0.f, 0.f};
#pragma unroll
        for (int kb = 0; kb < 4; ++kb)
            a = __builtin_amdgcn_mfma_f32_16x16x32_f16(a2fr[kb], bfr[kb], a, 0, 0, 0);
        int ib = wave * 16 + quad * 4;
        float p = 0.f;
#pragma unroll
        for (int r = 0; r < 4; ++r)
            p += fmaxf(a[r] + s_b2[ib + r], 0.f) * s_w3[ib + r];
        p += __shfl_xor(p, 16, 64);
        p += __shfl_xor(p, 32, 64);
        if (quad == 0) s_out[wave][nt * 16 + lrow] = p;
    }
    __syncthreads();

    if (tid < 64) {
        int oe = e_blk + tid;
        if (oe < E)
            out[oe] = b3[0] + s_out[0][tid] + s_out[1][tid]
                            + s_out[2][tid] + s_out[3][tid];
    }
}

extern "C" void kernel_launch(void* const* d_in, const int* in_sizes, int n_in,
                              void* d_out, int out_size, void* d_ws, size_t ws_size,
                              hipStream_t stream) {
    const float* x  = (const float*)d_in[0];
    const int*   ei = (const int*)d_in[1];   // int32 (verified round 1)
    const float* ew = (const float*)d_in[2];
    const float* W1 = (const float*)d_in[3];
    const float* b1 = (const float*)d_in[4];
    const float* W2 = (const float*)d_in[5];
    const float* b2 = (const float*)d_in[6];
    const float* W3 = (const float*)d_in[7];
    const float* b3 = (const float*)d_in[8];
    float* out = (float*)d_out;
    const int E = in_sizes[2];               // n_edges
    const int n_x = in_sizes[0];             // 3.2M floats
    const int n_x8 = n_x / 8;

    _Float16* wsh = (_Float16*)d_ws;                 // 24576 halves = 48 KiB
    _Float16* xh  = (_Float16*)((char*)d_ws + 49152); // fp16 x copy, 6.4 MB

    int xblk = (n_x8 + 255) / 256;
    prep_kernel<<<96 + xblk, 256, 0, stream>>>(x, W1, W2, wsh, xh, n_x8);

    int nblk = (E + 63) / 64;
    edge_mlp_kernel<<<nblk, 256, 0, stream>>>(xh, ei, ew, W1, b1, b2, W3, b3,
                                              wsh, out, E);
}

// Round 4
// 156.486 us; speedup vs baseline: 2.1492x; 1.5140x over previous
//
#include <hip/hip_runtime.h>

typedef _Float16 half8 __attribute__((ext_vector_type(8)));
typedef _Float16 half4_t __attribute__((ext_vector_type(4)));
typedef float floatx4 __attribute__((ext_vector_type(4)));

// h1 LDS tile: 128 rows (edges) x 128 halves (256 B rows). XOR swizzle:
// 16B-slot index ^= (row & 7)  <=>  half-col ^= (row&7)<<3.
__device__ __forceinline__ int swz(int row, int col) {
    return row * 128 + (col ^ ((row & 7) << 3));
}

// Prep: blocks [0,96) repack W1/W2 to MFMA A-frag order (fp16);
// block 96 packs fp32 params [b1(128) | W1[:,0](128) | b2(64) | W3(64)];
// blocks [97,..) convert x to fp16 (xh = L2/L3-resident 6.4 MB copy).
__global__ __launch_bounds__(256) void prep_kernel(
    const float* __restrict__ x,
    const float* __restrict__ W1, const float* __restrict__ W2,
    const float* __restrict__ b1, const float* __restrict__ b2,
    const float* __restrict__ W3,
    _Float16* __restrict__ wsh, float* __restrict__ pf,
    _Float16* __restrict__ xh, int n_x8)
{
    int b = blockIdx.x;
    if (b < 96) {
        int tid = b * 256 + threadIdx.x;
        if (tid < 16384) {                    // W1 cols 1..128: 8 mtiles x 4 kb x 512
            int c = tid >> 9, r = tid & 511;
            int L = r >> 3, jj = r & 7;
            int mt = c >> 2, kb = c & 3;
            int n = mt * 16 + (L & 15);
            int k = kb * 32 + (L >> 4) * 8 + jj;
            wsh[tid] = (_Float16)W1[n * 129 + 1 + k];
        } else {                              // W2: 4 itiles x 4 kb x 512
            int t = tid - 16384;
            int c = t >> 9, r = t & 511;
            int L = r >> 3, jj = r & 7;
            int it = c >> 2, kb = c & 3;
            int i = it * 16 + (L & 15);
            int j = kb * 32 + (L >> 4) * 8 + jj;
            wsh[tid] = (_Float16)W2[i * 128 + j];
        }
    } else if (b == 96) {
        for (int i = threadIdx.x; i < 384; i += 256) {
            float v;
            if (i < 128)      v = b1[i];
            else if (i < 256) v = W1[(i - 128) * 129];   // W1[:,0]
            else if (i < 320) v = b2[i - 256];
            else              v = W3[i - 320];
            pf[i] = v;
        }
    } else {
        int t2 = (b - 97) * 256 + threadIdx.x;
        if (t2 < n_x8) {
            const float4* p = (const float4*)(x + (size_t)t2 * 8);
            float4 v0 = p[0], v1 = p[1];
            half8 h = {(_Float16)v0.x, (_Float16)v0.y, (_Float16)v0.z, (_Float16)v0.w,
                       (_Float16)v1.x, (_Float16)v1.y, (_Float16)v1.z, (_Float16)v1.w};
            *(half8*)(xh + (size_t)t2 * 8) = h;
        }
    }
}

// Per-wave edge ownership: wave w owns edges [e_blk + w*32, +32).
// Layer-1 B-frags load DIRECTLY from xh (no LDS staging, no staging barrier);
// h1 handoff through LDS is wave-private (one barrier total); weights/biases
// come from L1-broadcast global loads (wf/pf). Register staging never crosses
// a barrier -> no spill pressure (rounds 2/3 lesson).
__global__ __launch_bounds__(256, 4) void edge_mlp_kernel(
    const _Float16* __restrict__ xh,
    const int* __restrict__ ei,
    const float* __restrict__ ew,
    const float* __restrict__ b3,
    const _Float16* __restrict__ wf,
    const float* __restrict__ pf,
    float* __restrict__ out, int E)
{
    __shared__ __align__(16) _Float16 hA[128 * 128];   // h1 [e][n], swizzled

    const int tid  = threadIdx.x;
    const int lane = tid & 63;
    const int wave = tid >> 6;
    const int lrow = lane & 15;
    const int quad = lane >> 4;
    const int e_blk = blockIdx.x * 128;

    // ---- per-lane edge indices + gather B-frags straight from xh ----
    int   eg[2];        // global edge ids (clamped)
    float ewv[2];
#pragma unroll
    for (int nt = 0; nt < 2; ++nt) {
        int e = e_blk + wave * 32 + nt * 16 + lrow;
        if (e >= E) e = E - 1;
        eg[nt] = e;
        ewv[nt] = ew[e];
    }
    half8 bfr[2][4];
#pragma unroll
    for (int nt = 0; nt < 2; ++nt) {
        int n0 = ei[eg[nt]];
        int n1 = ei[E + eg[nt]];
#pragma unroll
        for (int kb = 0; kb < 4; ++kb) {
            int node = (kb < 2) ? n0 : n1;
            bfr[nt][kb] = *(const half8*)(xh + (size_t)node * 64 + (kb & 1) * 32 + quad * 8);
        }
    }

    // ---- layer 1: for each W1 row-tile mt, D[n][e]; write h1 to hA ----
#pragma unroll
    for (int mt = 0; mt < 8; ++mt) {
        half8 afr[4];
#pragma unroll
        for (int kb = 0; kb < 4; ++kb)
            afr[kb] = *(const half8*)(wf + (mt * 4 + kb) * 512 + lane * 8);
        int nb = mt * 16 + quad * 4;
        float4 b1v = *(const float4*)(pf + nb);
        float4 c0v = *(const float4*)(pf + 128 + nb);
#pragma unroll
        for (int nt = 0; nt < 2; ++nt) {
            floatx4 a = {0.f, 0.f, 0.f, 0.f};
#pragma unroll
            for (int kb = 0; kb < 4; ++kb)
                a = __builtin_amdgcn_mfma_f32_16x16x32_f16(afr[kb], bfr[nt][kb], a, 0, 0, 0);
            half4_t hv;
            {
                float v0 = a[0] + b1v.x + ewv[nt] * c0v.x;
                float v1 = a[1] + b1v.y + ewv[nt] * c0v.y;
                float v2 = a[2] + b1v.z + ewv[nt] * c0v.z;
                float v3 = a[3] + b1v.w + ewv[nt] * c0v.w;
                hv[0] = (_Float16)fmaxf(v0, 0.f);
                hv[1] = (_Float16)fmaxf(v1, 0.f);
                hv[2] = (_Float16)fmaxf(v2, 0.f);
                hv[3] = (_Float16)fmaxf(v3, 0.f);
            }
            int row = wave * 32 + nt * 16 + lrow;
            *(half4_t*)(&hA[swz(row, nb)]) = hv;
        }
    }
    __syncthreads();   // h1 fully written (wave-private rows, but play safe)

    // ---- layer 2 (+fused layer 3) on this wave's 32 edges ----
    half8 b2fr[2][4];
#pragma unroll
    for (int nt = 0; nt < 2; ++nt) {
        int row = wave * 32 + nt * 16 + lrow;
#pragma unroll
        for (int kb = 0; kb < 4; ++kb)
            b2fr[nt][kb] = *(const half8*)(&hA[swz(row, kb * 32 + quad * 8)]);
    }

    const float b3v = b3[0];
    float tot[2] = {b3v, b3v};
#pragma unroll
    for (int it = 0; it < 4; ++it) {
        half8 a2[4];
#pragma unroll
        for (int kb = 0; kb < 4; ++kb)
            a2[kb] = *(const half8*)(wf + 16384 + (it * 4 + kb) * 512 + lane * 8);
        int ib = it * 16 + quad * 4;
        float4 b2v = *(const float4*)(pf + 256 + ib);
        float4 w3v = *(const float4*)(pf + 320 + ib);
#pragma unroll
        for (int nt = 0; nt < 2; ++nt) {
            floatx4 a = {0.f, 0.f, 0.f, 0.f};
#pragma unroll
            for (int kb = 0; kb < 4; ++kb)
                a = __builtin_amdgcn_mfma_f32_16x16x32_f16(a2[kb], b2fr[nt][kb], a, 0, 0, 0);
            float p = fmaxf(a[0] + b2v.x, 0.f) * w3v.x;
            p      += fmaxf(a[1] + b2v.y, 0.f) * w3v.y;
            p      += fmaxf(a[2] + b2v.z, 0.f) * w3v.z;
            p      += fmaxf(a[3] + b2v.w, 0.f) * w3v.w;
            p += __shfl_xor(p, 16, 64);
            p += __shfl_xor(p, 32, 64);
            tot[nt] += p;      // same order as old: b3 + it0 + it1 + it2 + it3
        }
    }

#pragma unroll
    for (int nt = 0; nt < 2; ++nt) {
        if (quad == 0) {
            int oe = e_blk + wave * 32 + nt * 16 + lrow;
            if (oe < E) out[oe] = tot[nt];
        }
    }
}

extern "C" void kernel_launch(void* const* d_in, const int* in_sizes, int n_in,
                              void* d_out, int out_size, void* d_ws, size_t ws_size,
                              hipStream_t stream) {
    const float* x  = (const float*)d_in[0];
    const int*   ei = (const int*)d_in[1];   // int32 (verified round 1)
    const float* ew = (const float*)d_in[2];
    const float* W1 = (const float*)d_in[3];
    const float* b1 = (const float*)d_in[4];
    const float* W2 = (const float*)d_in[5];
    const float* b2 = (const float*)d_in[6];
    const float* W3 = (const float*)d_in[7];
    const float* b3 = (const float*)d_in[8];
    float* out = (float*)d_out;
    const int E = in_sizes[2];               // n_edges
    const int n_x = in_sizes[0];             // 3.2M floats
    const int n_x8 = n_x / 8;

    _Float16* wsh = (_Float16*)d_ws;                  // 24576 halves = 48 KiB
    float*    pf  = (float*)((char*)d_ws + 49152);    // 384 fp32 params
    _Float16* xh  = (_Float16*)((char*)d_ws + 51200); // fp16 x copy, 6.4 MB

    int xblk = (n_x8 + 255) / 256;
    prep_kernel<<<97 + xblk, 256, 0, stream>>>(x, W1, W2, b1, b2, W3,
                                               wsh, pf, xh, n_x8);

    int nblk = (E + 127) / 128;
    edge_mlp_kernel<<<nblk, 256, 0, stream>>>(xh, ei, ew, b3, wsh, pf, out, E);
}

// Round 5
// 142.781 us; speedup vs baseline: 2.3555x; 1.0960x over previous
//
#include <hip/hip_runtime.h>

typedef _Float16 half8 __attribute__((ext_vector_type(8)));
typedef _Float16 half4_t __attribute__((ext_vector_type(4)));
typedef float floatx4 __attribute__((ext_vector_type(4)));

// LDS tile: 64 rows x 128 halves (256 B rows). XOR swizzle:
// 16B-slot index ^= (row & 7)  <=>  half-col ^= (row&7)<<3.
__device__ __forceinline__ int swz(int row, int col) {
    return row * 128 + (col ^ ((row & 7) << 3));
}

// Prep: blocks [0,96) repack W1/W2 to MFMA A-frag order (fp16);
// block 96 packs fp32 params [b1(128) | W1[:,0](128) | b2(64) | W3(64)];
// blocks [97,..) convert x to fp16 (xh = L2/L3-resident 6.4 MB copy).
__global__ __launch_bounds__(256) void prep_kernel(
    const float* __restrict__ x,
    const float* __restrict__ W1, const float* __restrict__ W2,
    const float* __restrict__ b1, const float* __restrict__ b2,
    const float* __restrict__ W3,
    _Float16* __restrict__ wsh, float* __restrict__ pf,
    _Float16* __restrict__ xh, int n_x8)
{
    int b = blockIdx.x;
    if (b < 96) {
        int tid = b * 256 + threadIdx.x;
        if (tid < 16384) {                    // W1 cols 1..128: 8 mtiles x 4 kb x 512
            int c = tid >> 9, r = tid & 511;
            int L = r >> 3, jj = r & 7;
            int mt = c >> 2, kb = c & 3;
            int n = mt * 16 + (L & 15);
            int k = kb * 32 + (L >> 4) * 8 + jj;
            wsh[tid] = (_Float16)W1[n * 129 + 1 + k];
        } else {                              // W2: 4 itiles x 4 kb x 512
            int t = tid - 16384;
            int c = t >> 9, r = t & 511;
            int L = r >> 3, jj = r & 7;
            int it = c >> 2, kb = c & 3;
            int i = it * 16 + (L & 15);
            int j = kb * 32 + (L >> 4) * 8 + jj;
            wsh[tid] = (_Float16)W2[i * 128 + j];
        }
    } else if (b == 96) {
        for (int i = threadIdx.x; i < 384; i += 256) {
            float v;
            if (i < 128)      v = b1[i];
            else if (i < 256) v = W1[(i - 128) * 129];   // W1[:,0]
            else if (i < 320) v = b2[i - 256];
            else              v = W3[i - 320];
            pf[i] = v;
        }
    } else {
        int t2 = (b - 97) * 256 + threadIdx.x;
        if (t2 < n_x8) {
            const float4* p = (const float4*)(x + (size_t)t2 * 8);
            float4 v0 = p[0], v1 = p[1];
            half8 h = {(_Float16)v0.x, (_Float16)v0.y, (_Float16)v0.z, (_Float16)v0.w,
                       (_Float16)v1.x, (_Float16)v1.y, (_Float16)v1.z, (_Float16)v1.w};
            *(half8*)(xh + (size_t)t2 * 8) = h;
        }
    }
}

// 64-edge tiles, ~17.4 KB LDS (hA 16K + s_out 1K) -> 8 blocks/CU if VGPR<=64.
// All scalar params (b1,c0,b2,W3,ew) come from L1-broadcast global loads, not
// LDS. Layer-1 runs as two sequential mi-passes reloading afr (16 VGPR live
// instead of 32) to keep total VGPR <= 64. launch_bounds(256,4): the compiler
// is NEVER forced to spill (rounds 2/3 lesson); occupancy comes from LDS+VGPR.
__global__ __launch_bounds__(256, 4) void edge_mlp_kernel(
    const _Float16* __restrict__ xh,
    const int* __restrict__ ei,
    const float* __restrict__ ew,
    const float* __restrict__ b3,
    const _Float16* __restrict__ wf,
    const float* __restrict__ pf,
    float* __restrict__ out, int E)
{
    __shared__ __align__(16) _Float16 hA[64 * 128];   // 16 KB, feats then h1
    __shared__ float s_out[4][64];                    // 1 KB

    const int tid  = threadIdx.x;
    const int lane = tid & 63;
    const int wave = tid >> 6;
    const int lrow = lane & 15;
    const int quad = lane >> 4;
    const int e_blk = blockIdx.x * 64;

    // ---- gather fp16 node rows -> hA: k 0..63 = src, 64..127 = tgt ----
    // thread t: edge row = t&63, part = (t>>6)&1, half-row = t>>7.
    // Each thread stages 64 B (4 x half8); 8 consecutive rows per 8-lane
    // phase hit 8 distinct swizzled 16B slots: conflict-free ds_write_b128.
    {
        int e_loc = tid & 63;
        int part = (tid >> 6) & 1;
        int half = tid >> 7;
        int e = e_blk + e_loc; if (e >= E) e = E - 1;
        int node = ei[(size_t)part * E + e];
        const _Float16* rp = xh + (size_t)node * 64 + half * 32;
        int r7 = (e_loc & 7) << 3;
        _Float16* dst = &hA[e_loc * 128];
        int base = part * 64 + half * 32;
#pragma unroll
        for (int q = 0; q < 4; ++q)
            *(half8*)(dst + ((base + q * 8) ^ r7)) = *(const half8*)(rp + q * 8);
    }

    // ---- per-lane edge-weight prefetch (quad-broadcast L1 loads) ----
    float ewv[4];
#pragma unroll
    for (int nt = 0; nt < 4; ++nt) {
        int e = e_blk + nt * 16 + lrow; if (e >= E) e = E - 1;
        ewv[nt] = ew[e];
    }
    const float b3v = b3[0];

    __syncthreads();

    // ---- layer 1: two passes, mt = 2*wave + mi; afr reloaded per pass ----
    half4_t h1v[2][4];
#pragma unroll
    for (int mi = 0; mi < 2; ++mi) {
        const int mt = 2 * wave + mi;
        half8 afr[4];
#pragma unroll
        for (int kb = 0; kb < 4; ++kb)
            afr[kb] = *(const half8*)(wf + (mt * 4 + kb) * 512 + lane * 8);
        int nb = mt * 16 + quad * 4;
        float4 b1v = *(const float4*)(pf + nb);
        float4 c0v = *(const float4*)(pf + 128 + nb);
#pragma unroll
        for (int nt = 0; nt < 4; ++nt) {
            int row = nt * 16 + lrow;
            half8 bfr[4];
#pragma unroll
            for (int kb = 0; kb < 4; ++kb)
                bfr[kb] = *(const half8*)(&hA[swz(row, kb * 32 + quad * 8)]);
            floatx4 a = {0.f, 0.f, 0.f, 0.f};
#pragma unroll
            for (int kb = 0; kb < 4; ++kb)
                a = __builtin_amdgcn_mfma_f32_16x16x32_f16(afr[kb], bfr[kb], a, 0, 0, 0);
            half4_t hv;
            hv[0] = (_Float16)fmaxf(a[0] + b1v.x + ewv[nt] * c0v.x, 0.f);
            hv[1] = (_Float16)fmaxf(a[1] + b1v.y + ewv[nt] * c0v.y, 0.f);
            hv[2] = (_Float16)fmaxf(a[2] + b1v.z + ewv[nt] * c0v.z, 0.f);
            hv[3] = (_Float16)fmaxf(a[3] + b1v.w + ewv[nt] * c0v.w, 0.f);
            h1v[mi][nt] = hv;
        }
    }
    __syncthreads();   // all hA feature reads complete — safe to alias

    // ---- write hidden1 (fp16) into hA space as [e][n], swizzled ----
#pragma unroll
    for (int mi = 0; mi < 2; ++mi) {
        int nb = (2 * wave + mi) * 16 + quad * 4;
#pragma unroll
        for (int nt = 0; nt < 4; ++nt)
            *(half4_t*)(&hA[swz(nt * 16 + lrow, nb)]) = h1v[mi][nt];
    }
    __syncthreads();

    // ---- layer 2 (+fused layer 3): wave handles i-tile = wave ----
    half8 a2[4];
#pragma unroll
    for (int kb = 0; kb < 4; ++kb)
        a2[kb] = *(const half8*)(wf + 16384 + (wave * 4 + kb) * 512 + lane * 8);
    int ib = wave * 16 + quad * 4;
    float4 b2v = *(const float4*)(pf + 256 + ib);
    float4 w3v = *(const float4*)(pf + 320 + ib);

#pragma unroll
    for (int nt = 0; nt < 4; ++nt) {
        int row = nt * 16 + lrow;
        half8 bfr[4];
#pragma unroll
        for (int kb = 0; kb < 4; ++kb)
            bfr[kb] = *(const half8*)(&hA[swz(row, kb * 32 + quad * 8)]);
        floatx4 a = {0.f, 0.f, 0.f, 0.f};
#pragma unroll
        for (int kb = 0; kb < 4; ++kb)
            a = __builtin_amdgcn_mfma_f32_16x16x32_f16(a2[kb], bfr[kb], a, 0, 0, 0);
        float p = fmaxf(a[0] + b2v.x, 0.f) * w3v.x;
        p      += fmaxf(a[1] + b2v.y, 0.f) * w3v.y;
        p      += fmaxf(a[2] + b2v.z, 0.f) * w3v.z;
        p      += fmaxf(a[3] + b2v.w, 0.f) * w3v.w;
        p += __shfl_xor(p, 16, 64);
        p += __shfl_xor(p, 32, 64);
        if (quad == 0) s_out[wave][nt * 16 + lrow] = p;
    }
    __syncthreads();

    if (tid < 64) {
        int oe = e_blk + tid;
        if (oe < E)
            out[oe] = b3v + s_out[0][tid] + s_out[1][tid]
                          + s_out[2][tid] + s_out[3][tid];
    }
}

extern "C" void kernel_launch(void* const* d_in, const int* in_sizes, int n_in,
                              void* d_out, int out_size, void* d_ws, size_t ws_size,
                              hipStream_t stream) {
    const float* x  = (const float*)d_in[0];
    const int*   ei = (const int*)d_in[1];   // int32 (verified round 1)
    const float* ew = (const float*)d_in[2];
    const float* W1 = (const float*)d_in[3];
    const float* b1 = (const float*)d_in[4];
    const float* W2 = (const float*)d_in[5];
    const float* b2 = (const float*)d_in[6];
    const float* W3 = (const float*)d_in[7];
    const float* b3 = (const float*)d_in[8];
    float* out = (float*)d_out;
    const int E = in_sizes[2];               // n_edges
    const int n_x = in_sizes[0];             // 3.2M floats
    const int n_x8 = n_x / 8;

    _Float16* wsh = (_Float16*)d_ws;                  // 24576 halves = 48 KiB
    float*    pf  = (float*)((char*)d_ws + 49152);    // 384 fp32 params
    _Float16* xh  = (_Float16*)((char*)d_ws + 51200); // fp16 x copy, 6.4 MB

    int xblk = (n_x8 + 255) / 256;
    prep_kernel<<<97 + xblk, 256, 0, stream>>>(x, W1, W2, b1, b2, W3,
                                               wsh, pf, xh, n_x8);

    int nblk = (E + 63) / 64;
    edge_mlp_kernel<<<nblk, 256, 0, stream>>>(xh, ei, ew, b3, wsh, pf, out, E);
}